// Round 12
// baseline (876.148 us; speedup 1.0000x reference)
//
#include <hip/hip_runtime.h>
#include <math.h>

#define N_NODES 50000
#define N_EDGES 800000
#define CAP 64                 // fixed CSR capacity/node (deg~Poisson(16))
#define RANGES 8
#define NODES_PER_RANGE 6250   // 50000 / 8
#define GEMMB 782              // ceil(50000/64)
#define CHUNKS (N_EDGES / 256) // 3125 edge chunks of 256
#define CPB 8                  // chunks per CSR block (latency batching)
#define BPR ((CHUNKS + CPB - 1) / CPB)   // 391 blocks per range
#define CSRB (BPR * RANGES)    // 3128 csr tasks
#define LROW 136               // LDS row stride in shorts (272 B)

typedef __attribute__((ext_vector_type(8))) short short8;   // 8 bf16
typedef __attribute__((ext_vector_type(4))) float f32x4;    // 4 fp32 acc

// ---------------- bf16 helpers (RNE) ----------------
__device__ __forceinline__ unsigned short f2bf(float f) {
    unsigned int u = __float_as_uint(f);
    return (unsigned short)((u + 0x7FFFu + ((u >> 16) & 1u)) >> 16);
}

// A fragment load: row-major fp32 (inline convert) or bf16.
template <bool F32>
__device__ __forceinline__ short8 loadA(const void* A, int off) {
    short8 r;
    if (F32) {
        const float* p = (const float*)A + off;   // 32B aligned
        float4 f0 = *(const float4*)p;
        float4 f1 = *(const float4*)(p + 4);
        r[0] = (short)f2bf(f0.x); r[1] = (short)f2bf(f0.y);
        r[2] = (short)f2bf(f0.z); r[3] = (short)f2bf(f0.w);
        r[4] = (short)f2bf(f1.x); r[5] = (short)f2bf(f1.y);
        r[6] = (short)f2bf(f1.z); r[7] = (short)f2bf(f1.w);
    } else {
        r = *(const short8*)((const unsigned short*)A + off);
    }
    return r;
}

// ---------------------------------------------------------------------------
// Forced-depth gather primitives (R9, verified): asm-pinned pipelined loads.
// Gather is at its traffic floor (~94MB compulsory fill = 8 XCDs x 12.8MB Y
// at ~1.4 TB/s random-128B fill); keep, stop tuning.
// ---------------------------------------------------------------------------
__device__ __forceinline__ void issue8(short8 (&v)[8],
    const unsigned short* a0, const unsigned short* a1) {
    asm volatile(
        "global_load_dwordx4 %0, %8, off\n\t"
        "global_load_dwordx4 %1, %8, off offset:16\n\t"
        "global_load_dwordx4 %2, %8, off offset:32\n\t"
        "global_load_dwordx4 %3, %8, off offset:48\n\t"
        "global_load_dwordx4 %4, %9, off\n\t"
        "global_load_dwordx4 %5, %9, off offset:16\n\t"
        "global_load_dwordx4 %6, %9, off offset:32\n\t"
        "global_load_dwordx4 %7, %9, off offset:48"
        : "=&v"(v[0]), "=&v"(v[1]), "=&v"(v[2]), "=&v"(v[3]),
          "=&v"(v[4]), "=&v"(v[5]), "=&v"(v[6]), "=&v"(v[7])
        : "v"(a0), "v"(a1));
}

__device__ __forceinline__ void wait_vm8(short8 (&v)[8]) {
    asm volatile("s_waitcnt vmcnt(8)"
        : "+v"(v[0]), "+v"(v[1]), "+v"(v[2]), "+v"(v[3]),
          "+v"(v[4]), "+v"(v[5]), "+v"(v[6]), "+v"(v[7]) :: "memory");
}

__device__ __forceinline__ void wait_vm0(short8 (&v)[8]) {
    asm volatile("s_waitcnt vmcnt(0)"
        : "+v"(v[0]), "+v"(v[1]), "+v"(v[2]), "+v"(v[3]),
          "+v"(v[4]), "+v"(v[5]), "+v"(v[6]), "+v"(v[7]) :: "memory");
}

__device__ __forceinline__ void consume8(short8 (&p)[4], const short8 (&v)[8]) {
    p[0] = __builtin_elementwise_max(p[0], v[0]);
    p[1] = __builtin_elementwise_max(p[1], v[1]);
    p[2] = __builtin_elementwise_max(p[2], v[2]);
    p[3] = __builtin_elementwise_max(p[3], v[3]);
    p[0] = __builtin_elementwise_max(p[0], v[4]);
    p[1] = __builtin_elementwise_max(p[1], v[5]);
    p[2] = __builtin_elementwise_max(p[2], v[6]);
    p[3] = __builtin_elementwise_max(p[3], v[7]);
}

// ---------------------------------------------------------------------------
// Phase bodies (byte-identical logic to the verified R9 kernels).
// ---------------------------------------------------------------------------
struct WDescs { const float* W[9]; int N[9]; };

__device__ __forceinline__ void do_prep(const WDescs& wd,
    unsigned short* __restrict__ Wpk, int* __restrict__ deg)
{
    const int nthr = gridDim.x * 256;
    const int tid = blockIdx.x * 256 + threadIdx.x;
    for (int id = tid; id < 9 * 16384; id += nthr) {
        int mi = id >> 14;
        int loc = id & 16383;
        int N = wd.N[mi];
        if (loc < 128 * N) {
            int c = loc / (N * 32);
            int n = (loc - c * N * 32) >> 5;
            int k = c * 32 + (loc & 31);
            Wpk[mi * 16384 + loc] = f2bf(wd.W[mi][k * N + n]);
        }
    }
    for (int i = tid; i < N_NODES; i += nthr) deg[i] = 0;
}

__device__ __forceinline__ void do_mix(int task,
    const int* __restrict__ esrc, const int* __restrict__ edst,
    int* __restrict__ deg, unsigned short* __restrict__ csr16,
    const float* __restrict__ x, const unsigned short* __restrict__ Wp1,
    const float* __restrict__ bp1, unsigned short* __restrict__ Y)
{
    if (task >= GEMMB) {
        const int b = task - GEMMB;
        const int range = b & (RANGES - 1);
        const int cbase = (b >> 3) * CPB;
        const int lo = range * NODES_PER_RANGE;
        int d[CPB], s[CPB];
        #pragma unroll
        for (int i = 0; i < CPB; ++i) {
            const int c = cbase + i;
            const int e = c * 256 + threadIdx.x;
            const bool ok = (c < CHUNKS);
            d[i] = ok ? edst[e] : -1;        // coalesced, 16 loads in flight
            s[i] = ok ? esrc[e] : 0;
        }
        #pragma unroll
        for (int i = 0; i < CPB; ++i) {
            if ((unsigned)(d[i] - lo) < (unsigned)NODES_PER_RANGE) {
                int r = atomicAdd(&deg[d[i]], 1);
                if (r < CAP) csr16[(d[i] << 6) + r] = (unsigned short)s[i];
            }
        }
        return;
    }
    const int lane = threadIdx.x & 63;
    const int wv = threadIdx.x >> 6;
    const int cl = lane & 15;
    const int quad = lane >> 4;
    const int rowBase = task * 64 + wv * 16;
    const int ar = min(rowBase + cl, N_NODES - 1);
    const int bLane = cl * 32 + quad * 8;

    f32x4 acc[8];
    #pragma unroll
    for (int t = 0; t < 8; ++t) acc[t] = (f32x4){0.f, 0.f, 0.f, 0.f};

    #pragma unroll
    for (int c = 0; c < 4; ++c) {
        short8 af = loadA<true>(x, ar * 128 + c * 32 + quad * 8);
        const unsigned short* Bc = Wp1 + c * 4096 + bLane;
        #pragma unroll
        for (int t = 0; t < 8; ++t) {
            short8 bf = *(const short8*)(Bc + t * 512);
            acc[t] = __builtin_amdgcn_mfma_f32_16x16x32_bf16(af, bf, acc[t], 0, 0, 0);
        }
    }
    const int row0 = rowBase + quad * 4;
    #pragma unroll
    for (int t = 0; t < 8; ++t) {
        float bc = bp1[t * 16 + cl];
        #pragma unroll
        for (int g = 0; g < 4; ++g) {
            int r = row0 + g;
            if (r < N_NODES)
                Y[r * 128 + t * 16 + cl] = f2bf(fmaxf(acc[t][g] + bc, 0.0f));
        }
    }
}

template <bool A0F32, bool LAST>
__device__ __forceinline__ void do_fused(int task, unsigned short* ldsAll,
    const void* __restrict__ A0,
    const unsigned short* __restrict__ Yl,
    const int* __restrict__ deg,
    const unsigned short* __restrict__ csr16,
    const unsigned short* __restrict__ B0, const unsigned short* __restrict__ B1,
    const float* __restrict__ bias,
    unsigned short* __restrict__ outH, float* __restrict__ outF,
    const unsigned short* __restrict__ Bnext, const float* __restrict__ bnext,
    unsigned short* __restrict__ Yout)
{
    constexpr int NT = LAST ? 4 : 8;
    constexpr int N = NT * 16;

    const int lane = threadIdx.x & 63;
    const int wv = threadIdx.x >> 6;
    const int cl = lane & 15;
    const int quad = lane >> 4;
    const int nodeBase = task * 64 + wv * 16;
    unsigned short* plw = ldsAll + wv * (16 * LROW);

    // ---- pool phase: 16 nodes/wave, 4 lanes/node, 32 dims/lane ----
    {
        const int n16 = lane >> 2;          // node within wave [0,16)
        const int g   = lane & 3;           // 64B dim slice [0,4)
        const int node = nodeBase + n16;
        const int nodeC = min(node, N_NODES - 1);
        const int myDeg = (node < N_NODES) ? min(deg[node], CAP) : 0;
        const unsigned short* csrn = csr16 + (nodeC << 6);
        const unsigned short* yg = Yl + g * 32;

        short8 p[4];
        p[0] = (short8){0,0,0,0,0,0,0,0};
        p[1] = p[0]; p[2] = p[0]; p[3] = p[0];

        if (myDeg > 0) {
            unsigned int idxw[16];
            *(uint4*)(idxw +  0) = *(const uint4*)(csrn +  0);
            *(uint4*)(idxw +  4) = *(const uint4*)(csrn +  8);
            *(uint4*)(idxw +  8) = *(const uint4*)(csrn + 16);
            *(uint4*)(idxw + 12) = *(const uint4*)(csrn + 24);
            const int s0 = (int)(idxw[0] & 0xFFFFu);   // edge 0 always valid

            auto eaddr = [&](int jj) -> const unsigned short* {
                int sj = (jj & 1) ? (int)(idxw[jj >> 1] >> 16)
                                  : (int)(idxw[jj >> 1] & 0xFFFFu);
                sj = (jj < myDeg) ? sj : s0;            // cndmask clamp
                return yg + (sj << 7);
            };

            short8 va[8], vb[8];
            issue8(va, eaddr(0),  eaddr(1));
            issue8(vb, eaddr(2),  eaddr(3));
            wait_vm8(va); consume8(p, va); issue8(va, eaddr(4),  eaddr(5));
            wait_vm8(vb); consume8(p, vb); issue8(vb, eaddr(6),  eaddr(7));
            wait_vm8(va); consume8(p, va); issue8(va, eaddr(8),  eaddr(9));
            wait_vm8(vb); consume8(p, vb); issue8(vb, eaddr(10), eaddr(11));
            wait_vm8(va); consume8(p, va); issue8(va, eaddr(12), eaddr(13));
            wait_vm8(vb); consume8(p, vb); issue8(vb, eaddr(14), eaddr(15));
            if (myDeg > 16) {
                wait_vm8(va); consume8(p, va); issue8(va, eaddr(16), eaddr(17));
                wait_vm8(vb); consume8(p, vb); issue8(vb, eaddr(18), eaddr(19));
                wait_vm8(va); consume8(p, va); issue8(va, eaddr(20), eaddr(21));
                wait_vm8(vb); consume8(p, vb); issue8(vb, eaddr(22), eaddr(23));
                wait_vm8(va); consume8(p, va); issue8(va, eaddr(24), eaddr(25));
                wait_vm8(vb); consume8(p, vb); issue8(vb, eaddr(26), eaddr(27));
                wait_vm8(va); consume8(p, va); issue8(va, eaddr(28), eaddr(29));
                wait_vm8(vb); consume8(p, vb); issue8(vb, eaddr(30), eaddr(31));
            }
            wait_vm8(va); consume8(p, va);
            wait_vm0(vb); consume8(p, vb);

            for (int k = 32; k < myDeg; ++k) {         // rare tail (P~1e-4)
                const short8* r = (const short8*)(yg + ((int)csrn[k] << 7));
                p[0] = __builtin_elementwise_max(p[0], r[0]);
                p[1] = __builtin_elementwise_max(p[1], r[1]);
                p[2] = __builtin_elementwise_max(p[2], r[2]);
                p[3] = __builtin_elementwise_max(p[3], r[3]);
            }
        }
        unsigned short* pw = plw + n16 * LROW + g * 32;
        *(short8*)(pw)      = p[0];
        *(short8*)(pw + 8)  = p[1];
        *(short8*)(pw + 16) = p[2];
        *(short8*)(pw + 24) = p[3];
        // no barrier: this wave wrote rows it alone will read (DS in-order)
    }

    const int ar = min(nodeBase + cl, N_NODES - 1);
    const int aBase = ar * 128 + quad * 8;
    const int fBase = cl * LROW + quad * 8;     // LDS A-fragment base
    const int bLane = cl * 32 + quad * 8;

    f32x4 acc[NT];
    #pragma unroll
    for (int t = 0; t < NT; ++t) acc[t] = (f32x4){0.f, 0.f, 0.f, 0.f};

    #pragma unroll
    for (int c = 0; c < 4; ++c) {
        short8 a0 = loadA<A0F32>(A0, aBase + c * 32);
        short8 a1 = *(const short8*)(plw + fBase + c * 32);
        const unsigned short* B0c = B0 + c * (N * 32) + bLane;
        const unsigned short* B1c = B1 + c * (N * 32) + bLane;
        #pragma unroll
        for (int t = 0; t < NT; ++t) {
            short8 bf = *(const short8*)(B0c + t * 512);
            acc[t] = __builtin_amdgcn_mfma_f32_16x16x32_bf16(a0, bf, acc[t], 0, 0, 0);
        }
        #pragma unroll
        for (int t = 0; t < NT; ++t) {
            short8 bf = *(const short8*)(B1c + t * 512);
            acc[t] = __builtin_amdgcn_mfma_f32_16x16x32_bf16(a1, bf, acc[t], 0, 0, 0);
        }
    }

    #pragma unroll
    for (int t = 0; t < NT; ++t) {
        float bc = bias[t * 16 + cl];
        #pragma unroll
        for (int g = 0; g < 4; ++g) acc[t][g] += bc;
    }

    // ---- fused row-wise L2 norm ----
    float inv[4];
    #pragma unroll
    for (int g = 0; g < 4; ++g) {
        float s = 0.f;
        #pragma unroll
        for (int t = 0; t < NT; ++t) s += acc[t][g] * acc[t][g];
        s += __shfl_xor(s, 1, 64);
        s += __shfl_xor(s, 2, 64);
        s += __shfl_xor(s, 4, 64);
        s += __shfl_xor(s, 8, 64);
        inv[g] = 1.0f / fmaxf(sqrtf(s), 1e-12f);
    }

    const int row0 = nodeBase + quad * 4;

    if (LAST) {
        #pragma unroll
        for (int t = 0; t < NT; ++t)
            #pragma unroll
            for (int g = 0; g < 4; ++g) {
                int r = row0 + g;
                if (r < N_NODES)
                    outF[r * N + t * 16 + cl] = fmaxf(acc[t][g] * inv[g], 0.0f);
            }
        return;
    }

    // h -> global (next layer's A0) + LDS stage (C-layout -> A-layout)
    #pragma unroll
    for (int t = 0; t < NT; ++t)
        #pragma unroll
        for (int g = 0; g < 4; ++g) {
            int r = row0 + g;
            unsigned short h = f2bf(fmaxf(acc[t][g] * inv[g], 0.0f));
            if (r < N_NODES) outH[r * 128 + t * 16 + cl] = h;
            plw[(quad * 4 + g) * LROW + t * 16 + cl] = h;
        }

    // ---- y-GEMM for the next layer ----
    f32x4 ya[8];
    #pragma unroll
    for (int t = 0; t < 8; ++t) ya[t] = (f32x4){0.f, 0.f, 0.f, 0.f};
    #pragma unroll
    for (int c = 0; c < 4; ++c) {
        short8 af = *(const short8*)(plw + cl * LROW + c * 32 + quad * 8);
        const unsigned short* Bc = Bnext + c * 4096 + bLane;
        #pragma unroll
        for (int t = 0; t < 8; ++t) {
            short8 bf = *(const short8*)(Bc + t * 512);
            ya[t] = __builtin_amdgcn_mfma_f32_16x16x32_bf16(af, bf, ya[t], 0, 0, 0);
        }
    }
    #pragma unroll
    for (int t = 0; t < 8; ++t) {
        float bc = bnext[t * 16 + cl];
        #pragma unroll
        for (int g = 0; g < 4; ++g) {
            int r = row0 + g;
            if (r < N_NODES)
                Yout[r * 128 + t * 16 + cl] = f2bf(fmaxf(ya[t][g] + bc, 0.0f));
        }
    }
}

// ---------------------------------------------------------------------------
// Standalone prep / mix dispatches (R9 shapes -- mix keeps its 3910-block
// high-occupancy form; R11 lesson: persistent-grid CSR lost 5x concurrency).
// ---------------------------------------------------------------------------
__global__ __launch_bounds__(256) void prep_kernel(
    WDescs wd, unsigned short* __restrict__ Wpk, int* __restrict__ deg)
{
    do_prep(wd, Wpk, deg);
}

__global__ __launch_bounds__(256) void mix_kernel(
    const int* __restrict__ esrc, const int* __restrict__ edst,
    int* __restrict__ deg, unsigned short* __restrict__ csr16,
    const float* __restrict__ x, const unsigned short* __restrict__ Wp1,
    const float* __restrict__ bp1, unsigned short* __restrict__ Y)
{
    do_mix(blockIdx.x, esrc, edst, deg, csr16, x, Wp1, bp1, Y);
}

// ---------------------------------------------------------------------------
// R12 mega3: the 3 fused layers in ONE persistent launch, 2 grid barriers
// replacing 2 dispatch gaps (~14us each, R9 sum-vs-total residual).
// vs R11's failed mega: (a) amdgpu_waves_per_eu(4,4) -- min 4 waves/EU caps
// VGPR at 128 (co-residency: 4 blk/CU x 256 CUs = 1024 >= 782, LDS 69.6KB
// <= 160KB), max 4 forbids the squeeze-to-64-VGPR spill R11 showed;
// (b) fused phases are exactly 1 task/block at grid 782 -- zero concurrency
// loss vs the standalone dispatches; (c) NO runtime occupancy queries (they
// took different paths in timed vs profiled runs) -- residency is
// guaranteed by construction, mega path runs unconditionally.
// Barrier: per-phase arrival counters + generation word; release/acquire
// agent-scope atomics + __threadfence (gfx950 wbL2/inv) for cross-XCD
// visibility of Y/H between layers.
// ---------------------------------------------------------------------------
__device__ __forceinline__ void gridbar(int* bar, int nb, int phase) {
    __syncthreads();
    if (threadIdx.x == 0) {
        __threadfence();                       // release my phase writes
        if (__hip_atomic_fetch_add(&bar[phase], 1, __ATOMIC_RELEASE,
                                   __HIP_MEMORY_SCOPE_AGENT) == nb - 1) {
            __hip_atomic_fetch_add(&bar[7], 1, __ATOMIC_RELEASE,
                                   __HIP_MEMORY_SCOPE_AGENT);
        } else {
            while (__hip_atomic_load(&bar[7], __ATOMIC_ACQUIRE,
                                     __HIP_MEMORY_SCOPE_AGENT) <= phase)
                __builtin_amdgcn_s_sleep(8);
        }
        __threadfence();                       // acquire others' writes
    }
    __syncthreads();
}

__global__ __launch_bounds__(256)
__attribute__((amdgpu_waves_per_eu(4, 4)))
void mega3_kernel(
    const float* x, const int* deg, const unsigned short* csr16,
    const unsigned short* Wpk,
    unsigned short* YA, unsigned short* YB,
    unsigned short* H1, unsigned short* H2,
    int* bar,
    const float* b1, const float* b2, const float* b3,
    const float* bp2, const float* bp3,
    float* outF)
{
    __shared__ unsigned short lds[4][16 * LROW];   // 17.4 KB
    unsigned short* ldsAll = &lds[0][0];
    const int task = blockIdx.x;                   // 1 task/block, all layers
    auto WHd = [&](int i) { return Wpk + i * 16384; };

    // layer 1 (gathers YA, A0 = x fp32) -> H1, YB
    do_fused<true, false>(task, ldsAll, x, YA, deg, csr16,
        WHd(1), WHd(2), b1, H1, nullptr, WHd(3), bp2, YB);
    gridbar(bar, gridDim.x, 0);
    // layer 2 (gathers YB, A0 = H1) -> H2, YA
    do_fused<false, false>(task, ldsAll, H1, YB, deg, csr16,
        WHd(4), WHd(5), b2, H2, nullptr, WHd(6), bp3, YA);
    gridbar(bar, gridDim.x, 1);
    // layer 3 (gathers YA, A0 = H2) -> fp32 out
    do_fused<false, true>(task, ldsAll, H2, YA, deg, csr16,
        WHd(7), WHd(8), b3, nullptr, outF, nullptr, nullptr, nullptr);
}

extern "C" void kernel_launch(void* const* d_in, const int* in_sizes, int n_in,
                              void* d_out, int out_size, void* d_ws, size_t ws_size,
                              hipStream_t stream) {
    const float* x    = (const float*)d_in[0];
    const int*   esrc = (const int*)d_in[1];
    const int*   edst = (const int*)d_in[2];
    const float* Wp[3], *bp[3], *Ws[3], *Wn[3], *bb[3];
    for (int l = 0; l < 3; ++l) {
        Wp[l] = (const float*)d_in[3 + 5 * l];
        bp[l] = (const float*)d_in[4 + 5 * l];
        Ws[l] = (const float*)d_in[5 + 5 * l];
        Wn[l] = (const float*)d_in[6 + 5 * l];
        bb[l] = (const float*)d_in[7 + 5 * l];
    }

    const int NF = N_NODES * 128;
    unsigned short* YA  = (unsigned short*)d_ws;     // y ping
    unsigned short* YB  = YA + NF;                   // y pong
    unsigned short* PL  = YB + NF;                   // (unused; kept for layout)
    unsigned short* H1  = PL + NF;                   // h1
    unsigned short* H2  = H1 + NF;                   // h2
    unsigned short* Wpk = H2 + NF;                   // 9 * 16384 packed weights
    int* deg = (int*)(Wpk + 9 * 16384);              // 50000
    unsigned short* csr16 = (unsigned short*)(deg + N_NODES); // 50000*64
    int* bar = (int*)(csr16 + N_NODES * CAP);        // 8 ints (barrier)

    auto WH = [&](int i) { return Wpk + i * 16384; };
    // order: 0=Wp1 1=Ws1 2=Wn1 3=Wp2 4=Ws2 5=Wn2 6=Wp3 7=Ws3 8=Wn3

    WDescs wd;
    wd.W[0] = Wp[0]; wd.N[0] = 128;
    wd.W[1] = Ws[0]; wd.N[1] = 128;
    wd.W[2] = Wn[0]; wd.N[2] = 128;
    wd.W[3] = Wp[1]; wd.N[3] = 128;
    wd.W[4] = Ws[1]; wd.N[4] = 128;
    wd.W[5] = Wn[1]; wd.N[5] = 128;
    wd.W[6] = Wp[2]; wd.N[6] = 128;
    wd.W[7] = Ws[2]; wd.N[7] = 64;
    wd.W[8] = Wn[2]; wd.N[8] = 64;

    // 1) prep: pack weights + zero deg
    prep_kernel<<<576, 256, 0, stream>>>(wd, Wpk, deg);
    // 2) Y1 = relu(x@Wp1+bp1) + one-shot CSR fill (R1 best-measured form)
    mix_kernel<<<GEMMB + CSRB, 256, 0, stream>>>(esrc, edst, deg, csr16,
                                                 x, WH(0), bp[0], YA);
    // 3) barrier state reset (capture-legal) + all 3 layers in one launch
    hipMemsetAsync(bar, 0, 8 * sizeof(int), stream);
    mega3_kernel<<<GEMMB, 256, 0, stream>>>(
        x, deg, csr16, Wpk, YA, YB, H1, H2, bar,
        bb[0], bb[1], bb[2], bp[1], bp[2], (float*)d_out);
}

// Round 14
// 319.555 us; speedup vs baseline: 2.7418x; 2.7418x over previous
//
#include <hip/hip_runtime.h>
#include <math.h>

#define N_NODES 50000
#define N_EDGES 800000
#define CAP 64                 // fixed CSR capacity/node (deg~Poisson(16))
#define RANGES 8
#define NODES_PER_RANGE 6250   // 50000 / 8
#define GEMMB 782              // ceil(50000/64) (mix GEMM blocks, 256 thr)
#define CHUNKS (N_EDGES / 256) // 3125 edge chunks of 256
#define CPB 8                  // chunks per CSR block (latency batching)
#define BPR ((CHUNKS + CPB - 1) / CPB)   // 391 blocks per range
#define CSRB (BPR * RANGES)    // 3128 csr blocks
#define LROW 136               // LDS row stride in shorts (272 B)
#define FWAVES 2               // fused: 2 waves/block (R13 tail-trim)
#define FTPB (FWAVES * 64)     // 128 threads
#define FNPB (FWAVES * 16)     // 32 nodes/block
#define FGRID ((N_NODES + FNPB - 1) / FNPB)   // 1563 fused blocks

typedef __attribute__((ext_vector_type(8))) short short8;   // 8 bf16
typedef __attribute__((ext_vector_type(4))) float f32x4;    // 4 fp32 acc

// ---------------- bf16 helpers (RNE) ----------------
__device__ __forceinline__ unsigned short f2bf(float f) {
    unsigned int u = __float_as_uint(f);
    return (unsigned short)((u + 0x7FFFu + ((u >> 16) & 1u)) >> 16);
}

// A fragment load: row-major fp32 (inline convert) or bf16.
template <bool F32>
__device__ __forceinline__ short8 loadA(const void* A, int off) {
    short8 r;
    if (F32) {
        const float* p = (const float*)A + off;   // 32B aligned
        float4 f0 = *(const float4*)p;
        float4 f1 = *(const float4*)(p + 4);
        r[0] = (short)f2bf(f0.x); r[1] = (short)f2bf(f0.y);
        r[2] = (short)f2bf(f0.z); r[3] = (short)f2bf(f0.w);
        r[4] = (short)f2bf(f1.x); r[5] = (short)f2bf(f1.y);
        r[6] = (short)f2bf(f1.z); r[7] = (short)f2bf(f1.w);
    } else {
        r = *(const short8*)((const unsigned short*)A + off);
    }
    return r;
}

// ---------------------------------------------------------------------------
// Forced-depth gather primitives (R9, verified): asm-pinned pipelined loads.
// Gather traffic is compulsory (~94MB = 8 XCDs x 12.8MB Y); R9 proved
// deeper per-lane pipelining doesn't move it. Kept as-is.
// ---------------------------------------------------------------------------
__device__ __forceinline__ void issue8(short8 (&v)[8],
    const unsigned short* a0, const unsigned short* a1) {
    asm volatile(
        "global_load_dwordx4 %0, %8, off\n\t"
        "global_load_dwordx4 %1, %8, off offset:16\n\t"
        "global_load_dwordx4 %2, %8, off offset:32\n\t"
        "global_load_dwordx4 %3, %8, off offset:48\n\t"
        "global_load_dwordx4 %4, %9, off\n\t"
        "global_load_dwordx4 %5, %9, off offset:16\n\t"
        "global_load_dwordx4 %6, %9, off offset:32\n\t"
        "global_load_dwordx4 %7, %9, off offset:48"
        : "=&v"(v[0]), "=&v"(v[1]), "=&v"(v[2]), "=&v"(v[3]),
          "=&v"(v[4]), "=&v"(v[5]), "=&v"(v[6]), "=&v"(v[7])
        : "v"(a0), "v"(a1));
}

__device__ __forceinline__ void wait_vm8(short8 (&v)[8]) {
    asm volatile("s_waitcnt vmcnt(8)"
        : "+v"(v[0]), "+v"(v[1]), "+v"(v[2]), "+v"(v[3]),
          "+v"(v[4]), "+v"(v[5]), "+v"(v[6]), "+v"(v[7]) :: "memory");
}

__device__ __forceinline__ void wait_vm0(short8 (&v)[8]) {
    asm volatile("s_waitcnt vmcnt(0)"
        : "+v"(v[0]), "+v"(v[1]), "+v"(v[2]), "+v"(v[3]),
          "+v"(v[4]), "+v"(v[5]), "+v"(v[6]), "+v"(v[7]) :: "memory");
}

__device__ __forceinline__ void consume8(short8 (&p)[4], const short8 (&v)[8]) {
    p[0] = __builtin_elementwise_max(p[0], v[0]);
    p[1] = __builtin_elementwise_max(p[1], v[1]);
    p[2] = __builtin_elementwise_max(p[2], v[2]);
    p[3] = __builtin_elementwise_max(p[3], v[3]);
    p[0] = __builtin_elementwise_max(p[0], v[4]);
    p[1] = __builtin_elementwise_max(p[1], v[5]);
    p[2] = __builtin_elementwise_max(p[2], v[6]);
    p[3] = __builtin_elementwise_max(p[3], v[7]);
}

// ---------------------------------------------------------------------------
// prep: pack 9 weight matrices fp32 -> bf16 fragment layout; zero deg.
// ---------------------------------------------------------------------------
struct WDescs { const float* W[9]; int N[9]; };

__global__ __launch_bounds__(256) void prep_kernel(
    WDescs wd, unsigned short* __restrict__ Wpk, int* __restrict__ deg)
{
    const int nthr = gridDim.x * 256;
    const int tid = blockIdx.x * 256 + threadIdx.x;
    for (int id = tid; id < 9 * 16384; id += nthr) {
        int mi = id >> 14;
        int loc = id & 16383;
        int N = wd.N[mi];
        if (loc < 128 * N) {
            int c = loc / (N * 32);
            int n = (loc - c * N * 32) >> 5;
            int k = c * 32 + (loc & 31);
            Wpk[mi * 16384 + loc] = f2bf(wd.W[mi][k * N + n]);
        }
    }
    for (int i = tid; i < N_NODES; i += nthr) deg[i] = 0;
}

// ---------------------------------------------------------------------------
// mix (R1 best-measured form, ~50us): blocks [0,GEMMB) compute
// Y1 = relu(x@Wp1+bp1); blocks [GEMMB,+CSRB) build CSR one-shot.
// R1-R3: issue-side restructuring moved mix 50<->59us; the cost is the
// scattered-atomic/scatter-store machinery itself. Frozen.
// ---------------------------------------------------------------------------
__global__ __launch_bounds__(256) void mix_kernel(
    const int* __restrict__ esrc, const int* __restrict__ edst,
    int* __restrict__ deg, unsigned short* __restrict__ csr16,
    const float* __restrict__ x, const unsigned short* __restrict__ Wp1,
    const float* __restrict__ bp1, unsigned short* __restrict__ Y)
{
    if (blockIdx.x >= GEMMB) {
        const int b = blockIdx.x - GEMMB;
        const int range = b & (RANGES - 1);
        const int cbase = (b >> 3) * CPB;
        const int lo = range * NODES_PER_RANGE;
        int d[CPB], s[CPB];
        #pragma unroll
        for (int i = 0; i < CPB; ++i) {
            const int c = cbase + i;
            const int e = c * 256 + threadIdx.x;
            const bool ok = (c < CHUNKS);
            d[i] = ok ? edst[e] : -1;        // coalesced, 16 loads in flight
            s[i] = ok ? esrc[e] : 0;
        }
        #pragma unroll
        for (int i = 0; i < CPB; ++i) {
            if ((unsigned)(d[i] - lo) < (unsigned)NODES_PER_RANGE) {
                int r = atomicAdd(&deg[d[i]], 1);
                if (r < CAP) csr16[(d[i] << 6) + r] = (unsigned short)s[i];
            }
        }
        return;
    }
    const int lane = threadIdx.x & 63;
    const int wv = threadIdx.x >> 6;
    const int cl = lane & 15;
    const int quad = lane >> 4;
    const int rowBase = blockIdx.x * 64 + wv * 16;
    const int ar = min(rowBase + cl, N_NODES - 1);
    const int bLane = cl * 32 + quad * 8;

    f32x4 acc[8];
    #pragma unroll
    for (int t = 0; t < 8; ++t) acc[t] = (f32x4){0.f, 0.f, 0.f, 0.f};

    #pragma unroll
    for (int c = 0; c < 4; ++c) {
        short8 af = loadA<true>(x, ar * 128 + c * 32 + quad * 8);
        const unsigned short* Bc = Wp1 + c * 4096 + bLane;
        #pragma unroll
        for (int t = 0; t < 8; ++t) {
            short8 bf = *(const short8*)(Bc + t * 512);
            acc[t] = __builtin_amdgcn_mfma_f32_16x16x32_bf16(af, bf, acc[t], 0, 0, 0);
        }
    }
    const int row0 = rowBase + quad * 4;
    #pragma unroll
    for (int t = 0; t < 8; ++t) {
        float bc = bp1[t * 16 + cl];
        #pragma unroll
        for (int g = 0; g < 4; ++g) {
            int r = row0 + g;
            if (r < N_NODES)
                Y[r * 128 + t * 16 + cl] = f2bf(fmaxf(acc[t][g] + bc, 0.0f));
        }
    }
}

// ---------------------------------------------------------------------------
// fused: max-pool + dual-GEMM + l2norm + (next-layer y-GEMM | fp32 out).
// R13 change vs R9 (body byte-identical): block = 2 waves / 128 threads,
// grid 1563 (was 4 waves / 782). R9 counters: occupancy 15-23% vs a
// grid-imposed 38% ceiling; 782 = 256*3+14 -> 14 CUs run a 4th block while
// 242 idle (tail ~ 1/4 of CU work). 1563 = 256*6+27 -> tail ~ 1/7.
// Resident waves/CU unchanged (12.2) -- pure load-balance trim.
// ---------------------------------------------------------------------------
template <bool A0F32, bool LAST>
__device__ __forceinline__ void do_fused(int task, unsigned short* ldsAll,
    const void* __restrict__ A0,
    const unsigned short* __restrict__ Yl,
    const int* __restrict__ deg,
    const unsigned short* __restrict__ csr16,
    const unsigned short* __restrict__ B0, const unsigned short* __restrict__ B1,
    const float* __restrict__ bias,
    unsigned short* __restrict__ outH, float* __restrict__ outF,
    const unsigned short* __restrict__ Bnext, const float* __restrict__ bnext,
    unsigned short* __restrict__ Yout)
{
    constexpr int NT = LAST ? 4 : 8;
    constexpr int N = NT * 16;

    const int lane = threadIdx.x & 63;
    const int wv = threadIdx.x >> 6;
    const int cl = lane & 15;
    const int quad = lane >> 4;
    const int nodeBase = task * FNPB + wv * 16;
    unsigned short* plw = ldsAll + wv * (16 * LROW);

    // ---- pool phase: 16 nodes/wave, 4 lanes/node, 32 dims/lane ----
    {
        const int n16 = lane >> 2;          // node within wave [0,16)
        const int g   = lane & 3;           // 64B dim slice [0,4)
        const int node = nodeBase + n16;
        const int nodeC = min(node, N_NODES - 1);
        const int myDeg = (node < N_NODES) ? min(deg[node], CAP) : 0;
        const unsigned short* csrn = csr16 + (nodeC << 6);
        const unsigned short* yg = Yl + g * 32;

        short8 p[4];
        p[0] = (short8){0,0,0,0,0,0,0,0};
        p[1] = p[0]; p[2] = p[0]; p[3] = p[0];

        if (myDeg > 0) {
            unsigned int idxw[16];
            *(uint4*)(idxw +  0) = *(const uint4*)(csrn +  0);
            *(uint4*)(idxw +  4) = *(const uint4*)(csrn +  8);
            *(uint4*)(idxw +  8) = *(const uint4*)(csrn + 16);
            *(uint4*)(idxw + 12) = *(const uint4*)(csrn + 24);
            const int s0 = (int)(idxw[0] & 0xFFFFu);   // edge 0 always valid

            auto eaddr = [&](int jj) -> const unsigned short* {
                int sj = (jj & 1) ? (int)(idxw[jj >> 1] >> 16)
                                  : (int)(idxw[jj >> 1] & 0xFFFFu);
                sj = (jj < myDeg) ? sj : s0;            // cndmask clamp
                return yg + (sj << 7);
            };

            short8 va[8], vb[8];
            issue8(va, eaddr(0),  eaddr(1));
            issue8(vb, eaddr(2),  eaddr(3));
            wait_vm8(va); consume8(p, va); issue8(va, eaddr(4),  eaddr(5));
            wait_vm8(vb); consume8(p, vb); issue8(vb, eaddr(6),  eaddr(7));
            wait_vm8(va); consume8(p, va); issue8(va, eaddr(8),  eaddr(9));
            wait_vm8(vb); consume8(p, vb); issue8(vb, eaddr(10), eaddr(11));
            wait_vm8(va); consume8(p, va); issue8(va, eaddr(12), eaddr(13));
            wait_vm8(vb); consume8(p, vb); issue8(vb, eaddr(14), eaddr(15));
            if (myDeg > 16) {
                wait_vm8(va); consume8(p, va); issue8(va, eaddr(16), eaddr(17));
                wait_vm8(vb); consume8(p, vb); issue8(vb, eaddr(18), eaddr(19));
                wait_vm8(va); consume8(p, va); issue8(va, eaddr(20), eaddr(21));
                wait_vm8(vb); consume8(p, vb); issue8(vb, eaddr(22), eaddr(23));
                wait_vm8(va); consume8(p, va); issue8(va, eaddr(24), eaddr(25));
                wait_vm8(vb); consume8(p, vb); issue8(vb, eaddr(26), eaddr(27));
                wait_vm8(va); consume8(p, va); issue8(va, eaddr(28), eaddr(29));
                wait_vm8(vb); consume8(p, vb); issue8(vb, eaddr(30), eaddr(31));
            }
            wait_vm8(va); consume8(p, va);
            wait_vm0(vb); consume8(p, vb);

            for (int k = 32; k < myDeg; ++k) {         // rare tail (P~1e-4)
                const short8* r = (const short8*)(yg + ((int)csrn[k] << 7));
                p[0] = __builtin_elementwise_max(p[0], r[0]);
                p[1] = __builtin_elementwise_max(p[1], r[1]);
                p[2] = __builtin_elementwise_max(p[2], r[2]);
                p[3] = __builtin_elementwise_max(p[3], r[3]);
            }
        }
        unsigned short* pw = plw + n16 * LROW + g * 32;
        *(short8*)(pw)      = p[0];
        *(short8*)(pw + 8)  = p[1];
        *(short8*)(pw + 16) = p[2];
        *(short8*)(pw + 24) = p[3];
        // no barrier: this wave wrote rows it alone will read (DS in-order)
    }

    const int ar = min(nodeBase + cl, N_NODES - 1);
    const int aBase = ar * 128 + quad * 8;
    const int fBase = cl * LROW + quad * 8;     // LDS A-fragment base
    const int bLane = cl * 32 + quad * 8;

    f32x4 acc[NT];
    #pragma unroll
    for (int t = 0; t < NT; ++t) acc[t] = (f32x4){0.f, 0.f, 0.f, 0.f};

    #pragma unroll
    for (int c = 0; c < 4; ++c) {
        short8 a0 = loadA<A0F32>(A0, aBase + c * 32);
        short8 a1 = *(const short8*)(plw + fBase + c * 32);
        const unsigned short* B0c = B0 + c * (N * 32) + bLane;
        const unsigned short* B1c = B1 + c * (N * 32) + bLane;
        #pragma unroll
        for (int t = 0; t < NT; ++t) {
            short8 bf = *(const short8*)(B0c + t * 512);
            acc[t] = __builtin_amdgcn_mfma_f32_16x16x32_bf16(a0, bf, acc[t], 0, 0, 0);
        }
        #pragma unroll
        for (int t = 0; t < NT; ++t) {
            short8 bf = *(const short8*)(B1c + t * 512);
            acc[t] = __builtin_amdgcn_mfma_f32_16x16x32_bf16(a1, bf, acc[t], 0, 0, 0);
        }
    }

    #pragma unroll
    for (int t = 0; t < NT; ++t) {
        float bc = bias[t * 16 + cl];
        #pragma unroll
        for (int g = 0; g < 4; ++g) acc[t][g] += bc;
    }

    // ---- fused row-wise L2 norm (wave-local shuffles, width-64) ----
    float inv[4];
    #pragma unroll
    for (int g = 0; g < 4; ++g) {
        float s = 0.f;
        #pragma unroll
        for (int t = 0; t < NT; ++t) s += acc[t][g] * acc[t][g];
        s += __shfl_xor(s, 1, 64);
        s += __shfl_xor(s, 2, 64);
        s += __shfl_xor(s, 4, 64);
        s += __shfl_xor(s, 8, 64);
        inv[g] = 1.0f / fmaxf(sqrtf(s), 1e-12f);
    }

    const int row0 = nodeBase + quad * 4;

    if (LAST) {
        #pragma unroll
        for (int t = 0; t < NT; ++t)
            #pragma unroll
            for (int g = 0; g < 4; ++g) {
                int r = row0 + g;
                if (r < N_NODES)
                    outF[r * N + t * 16 + cl] = fmaxf(acc[t][g] * inv[g], 0.0f);
            }
        return;
    }

    // h -> global (next layer's A0) + LDS stage (C-layout -> A-layout)
    #pragma unroll
    for (int t = 0; t < NT; ++t)
        #pragma unroll
        for (int g = 0; g < 4; ++g) {
            int r = row0 + g;
            unsigned short h = f2bf(fmaxf(acc[t][g] * inv[g], 0.0f));
            if (r < N_NODES) outH[r * 128 + t * 16 + cl] = h;
            plw[(quad * 4 + g) * LROW + t * 16 + cl] = h;
        }

    // ---- y-GEMM for the next layer ----
    f32x4 ya[8];
    #pragma unroll
    for (int t = 0; t < 8; ++t) ya[t] = (f32x4){0.f, 0.f, 0.f, 0.f};
    #pragma unroll
    for (int c = 0; c < 4; ++c) {
        short8 af = *(const short8*)(plw + cl * LROW + c * 32 + quad * 8);
        const unsigned short* Bc = Bnext + c * 4096 + bLane;
        #pragma unroll
        for (int t = 0; t < 8; ++t) {
            short8 bf = *(const short8*)(Bc + t * 512);
            ya[t] = __builtin_amdgcn_mfma_f32_16x16x32_bf16(af, bf, ya[t], 0, 0, 0);
        }
    }
    #pragma unroll
    for (int t = 0; t < 8; ++t) {
        float bc = bnext[t * 16 + cl];
        #pragma unroll
        for (int g = 0; g < 4; ++g) {
            int r = row0 + g;
            if (r < N_NODES)
                Yout[r * 128 + t * 16 + cl] = f2bf(fmaxf(ya[t][g] + bc, 0.0f));
        }
    }
}

template <bool A0F32, bool LAST>
__global__ __launch_bounds__(FTPB) void fused_kernel(
    const void* __restrict__ A0,
    const unsigned short* __restrict__ Yl,
    const int* __restrict__ deg,
    const unsigned short* __restrict__ csr16,
    const unsigned short* __restrict__ B0, const unsigned short* __restrict__ B1,
    const float* __restrict__ bias,
    unsigned short* __restrict__ outH, float* __restrict__ outF,
    const unsigned short* __restrict__ Bnext, const float* __restrict__ bnext,
    unsigned short* __restrict__ Yout)
{
    __shared__ unsigned short lds[FWAVES][16 * LROW];   // 8.7 KB
    do_fused<A0F32, LAST>(blockIdx.x, &lds[0][0], A0, Yl, deg, csr16,
                          B0, B1, bias, outH, outF, Bnext, bnext, Yout);
}

extern "C" void kernel_launch(void* const* d_in, const int* in_sizes, int n_in,
                              void* d_out, int out_size, void* d_ws, size_t ws_size,
                              hipStream_t stream) {
    const float* x    = (const float*)d_in[0];
    const int*   esrc = (const int*)d_in[1];
    const int*   edst = (const int*)d_in[2];
    const float* Wp[3], *bp[3], *Ws[3], *Wn[3], *bb[3];
    for (int l = 0; l < 3; ++l) {
        Wp[l] = (const float*)d_in[3 + 5 * l];
        bp[l] = (const float*)d_in[4 + 5 * l];
        Ws[l] = (const float*)d_in[5 + 5 * l];
        Wn[l] = (const float*)d_in[6 + 5 * l];
        bb[l] = (const float*)d_in[7 + 5 * l];
    }

    const int NF = N_NODES * 128;
    unsigned short* YA  = (unsigned short*)d_ws;     // y ping
    unsigned short* YB  = YA + NF;                   // y pong
    unsigned short* PL  = YB + NF;                   // (unused; kept for layout)
    unsigned short* H1  = PL + NF;                   // h1
    unsigned short* H2  = H1 + NF;                   // h2
    unsigned short* Wpk = H2 + NF;                   // 9 * 16384 packed weights
    int* deg = (int*)(Wpk + 9 * 16384);              // 50000
    unsigned short* csr16 = (unsigned short*)(deg + N_NODES); // 50000*64

    auto WH = [&](int i) { return Wpk + i * 16384; };
    // order: 0=Wp1 1=Ws1 2=Wn1 3=Wp2 4=Ws2 5=Wn2 6=Wp3 7=Ws3 8=Wn3

    WDescs wd;
    wd.W[0] = Wp[0]; wd.N[0] = 128;
    wd.W[1] = Ws[0]; wd.N[1] = 128;
    wd.W[2] = Wn[0]; wd.N[2] = 128;
    wd.W[3] = Wp[1]; wd.N[3] = 128;
    wd.W[4] = Ws[1]; wd.N[4] = 128;
    wd.W[5] = Wn[1]; wd.N[5] = 128;
    wd.W[6] = Wp[2]; wd.N[6] = 128;
    wd.W[7] = Ws[2]; wd.N[7] = 64;
    wd.W[8] = Wn[2]; wd.N[8] = 64;

    // 1) prep: pack weights + zero deg
    prep_kernel<<<576, 256, 0, stream>>>(wd, Wpk, deg);
    // 2) Y1 = relu(x@Wp1+bp1) + one-shot CSR fill (R1 best-measured form)
    mix_kernel<<<GEMMB + CSRB, 256, 0, stream>>>(esrc, edst, deg, csr16,
                                                 x, WH(0), bp[0], YA);
    // 3) layer 1 (pool fused): gathers YA, A0 = x (fp32)
    fused_kernel<true, false><<<FGRID, FTPB, 0, stream>>>(
        x, YA, deg, csr16, WH(1), WH(2), bb[0], H1, nullptr, WH(3), bp[1], YB);
    // 4) layer 2: gathers YB, A0 = H1
    fused_kernel<false, false><<<FGRID, FTPB, 0, stream>>>(
        H1, YB, deg, csr16, WH(4), WH(5), bb[1], H2, nullptr, WH(6), bp[2], YA);
    // 5) layer 3: gathers YA, A0 = H2, fp32 out
    fused_kernel<false, true><<<FGRID, FTPB, 0, stream>>>(
        H2, YA, deg, csr16, WH(7), WH(8), bb[2], nullptr, (float*)d_out,
        nullptr, nullptr, nullptr);
}

// Round 15
// 313.150 us; speedup vs baseline: 2.7979x; 1.0205x over previous
//
#include <hip/hip_runtime.h>
#include <math.h>

#define N_NODES 50000
#define N_EDGES 800000
#define CAP 64                 // fixed CSR capacity/node (deg~Poisson(16))
#define RANGES 8
#define NODES_PER_RANGE 6250   // 50000 / 8
#define GEMMB 782              // ceil(50000/64) (mix GEMM blocks, 256 thr)
#define CHUNKS (N_EDGES / 256) // 3125 edge chunks of 256
#define CPB 8                  // chunks per CSR block (latency batching)
#define BPR ((CHUNKS + CPB - 1) / CPB)   // 391 blocks per range
#define CSRB (BPR * RANGES)    // 3128 csr blocks
#define LROW 136               // LDS row stride in shorts (272 B)
#define FWAVES 1               // fused: 1 wave/block (R15 tail-trim step 2)
#define FTPB (FWAVES * 64)     // 64 threads
#define FNPB (FWAVES * 16)     // 16 nodes/block
#define FGRID ((N_NODES + FNPB - 1) / FNPB)   // 3125 fused blocks

typedef __attribute__((ext_vector_type(8))) short short8;   // 8 bf16
typedef __attribute__((ext_vector_type(4))) float f32x4;    // 4 fp32 acc

// ---------------- bf16 helpers (RNE) ----------------
__device__ __forceinline__ unsigned short f2bf(float f) {
    unsigned int u = __float_as_uint(f);
    return (unsigned short)((u + 0x7FFFu + ((u >> 16) & 1u)) >> 16);
}

// A fragment load: row-major fp32 (inline convert) or bf16.
template <bool F32>
__device__ __forceinline__ short8 loadA(const void* A, int off) {
    short8 r;
    if (F32) {
        const float* p = (const float*)A + off;   // 32B aligned
        float4 f0 = *(const float4*)p;
        float4 f1 = *(const float4*)(p + 4);
        r[0] = (short)f2bf(f0.x); r[1] = (short)f2bf(f0.y);
        r[2] = (short)f2bf(f0.z); r[3] = (short)f2bf(f0.w);
        r[4] = (short)f2bf(f1.x); r[5] = (short)f2bf(f1.y);
        r[6] = (short)f2bf(f1.z); r[7] = (short)f2bf(f1.w);
    } else {
        r = *(const short8*)((const unsigned short*)A + off);
    }
    return r;
}

// ---------------------------------------------------------------------------
// Forced-depth gather primitives (R9, verified): asm-pinned pipelined loads.
// Gather traffic is compulsory (~94MB = 8 XCDs x 12.8MB Y); R9 proved
// deeper per-lane pipelining doesn't move it. Kept as-is.
// ---------------------------------------------------------------------------
__device__ __forceinline__ void issue8(short8 (&v)[8],
    const unsigned short* a0, const unsigned short* a1) {
    asm volatile(
        "global_load_dwordx4 %0, %8, off\n\t"
        "global_load_dwordx4 %1, %8, off offset:16\n\t"
        "global_load_dwordx4 %2, %8, off offset:32\n\t"
        "global_load_dwordx4 %3, %8, off offset:48\n\t"
        "global_load_dwordx4 %4, %9, off\n\t"
        "global_load_dwordx4 %5, %9, off offset:16\n\t"
        "global_load_dwordx4 %6, %9, off offset:32\n\t"
        "global_load_dwordx4 %7, %9, off offset:48"
        : "=&v"(v[0]), "=&v"(v[1]), "=&v"(v[2]), "=&v"(v[3]),
          "=&v"(v[4]), "=&v"(v[5]), "=&v"(v[6]), "=&v"(v[7])
        : "v"(a0), "v"(a1));
}

__device__ __forceinline__ void wait_vm8(short8 (&v)[8]) {
    asm volatile("s_waitcnt vmcnt(8)"
        : "+v"(v[0]), "+v"(v[1]), "+v"(v[2]), "+v"(v[3]),
          "+v"(v[4]), "+v"(v[5]), "+v"(v[6]), "+v"(v[7]) :: "memory");
}

__device__ __forceinline__ void wait_vm0(short8 (&v)[8]) {
    asm volatile("s_waitcnt vmcnt(0)"
        : "+v"(v[0]), "+v"(v[1]), "+v"(v[2]), "+v"(v[3]),
          "+v"(v[4]), "+v"(v[5]), "+v"(v[6]), "+v"(v[7]) :: "memory");
}

__device__ __forceinline__ void consume8(short8 (&p)[4], const short8 (&v)[8]) {
    p[0] = __builtin_elementwise_max(p[0], v[0]);
    p[1] = __builtin_elementwise_max(p[1], v[1]);
    p[2] = __builtin_elementwise_max(p[2], v[2]);
    p[3] = __builtin_elementwise_max(p[3], v[3]);
    p[0] = __builtin_elementwise_max(p[0], v[4]);
    p[1] = __builtin_elementwise_max(p[1], v[5]);
    p[2] = __builtin_elementwise_max(p[2], v[6]);
    p[3] = __builtin_elementwise_max(p[3], v[7]);
}

// ---------------------------------------------------------------------------
// prep: pack 9 weight matrices fp32 -> bf16 fragment layout; zero deg.
// ---------------------------------------------------------------------------
struct WDescs { const float* W[9]; int N[9]; };

__global__ __launch_bounds__(256) void prep_kernel(
    WDescs wd, unsigned short* __restrict__ Wpk, int* __restrict__ deg)
{
    const int nthr = gridDim.x * 256;
    const int tid = blockIdx.x * 256 + threadIdx.x;
    for (int id = tid; id < 9 * 16384; id += nthr) {
        int mi = id >> 14;
        int loc = id & 16383;
        int N = wd.N[mi];
        if (loc < 128 * N) {
            int c = loc / (N * 32);
            int n = (loc - c * N * 32) >> 5;
            int k = c * 32 + (loc & 31);
            Wpk[mi * 16384 + loc] = f2bf(wd.W[mi][k * N + n]);
        }
    }
    for (int i = tid; i < N_NODES; i += nthr) deg[i] = 0;
}

// ---------------------------------------------------------------------------
// mix (R1 best-measured form, ~50us): blocks [0,GEMMB) compute
// Y1 = relu(x@Wp1+bp1); blocks [GEMMB,+CSRB) build CSR one-shot.
// R1-R3: issue-side restructuring moved mix 50<->59us; the cost is the
// scattered-atomic/scatter-store machinery itself. Frozen.
// ---------------------------------------------------------------------------
__global__ __launch_bounds__(256) void mix_kernel(
    const int* __restrict__ esrc, const int* __restrict__ edst,
    int* __restrict__ deg, unsigned short* __restrict__ csr16,
    const float* __restrict__ x, const unsigned short* __restrict__ Wp1,
    const float* __restrict__ bp1, unsigned short* __restrict__ Y)
{
    if (blockIdx.x >= GEMMB) {
        const int b = blockIdx.x - GEMMB;
        const int range = b & (RANGES - 1);
        const int cbase = (b >> 3) * CPB;
        const int lo = range * NODES_PER_RANGE;
        int d[CPB], s[CPB];
        #pragma unroll
        for (int i = 0; i < CPB; ++i) {
            const int c = cbase + i;
            const int e = c * 256 + threadIdx.x;
            const bool ok = (c < CHUNKS);
            d[i] = ok ? edst[e] : -1;        // coalesced, 16 loads in flight
            s[i] = ok ? esrc[e] : 0;
        }
        #pragma unroll
        for (int i = 0; i < CPB; ++i) {
            if ((unsigned)(d[i] - lo) < (unsigned)NODES_PER_RANGE) {
                int r = atomicAdd(&deg[d[i]], 1);
                if (r < CAP) csr16[(d[i] << 6) + r] = (unsigned short)s[i];
            }
        }
        return;
    }
    const int lane = threadIdx.x & 63;
    const int wv = threadIdx.x >> 6;
    const int cl = lane & 15;
    const int quad = lane >> 4;
    const int rowBase = blockIdx.x * 64 + wv * 16;
    const int ar = min(rowBase + cl, N_NODES - 1);
    const int bLane = cl * 32 + quad * 8;

    f32x4 acc[8];
    #pragma unroll
    for (int t = 0; t < 8; ++t) acc[t] = (f32x4){0.f, 0.f, 0.f, 0.f};

    #pragma unroll
    for (int c = 0; c < 4; ++c) {
        short8 af = loadA<true>(x, ar * 128 + c * 32 + quad * 8);
        const unsigned short* Bc = Wp1 + c * 4096 + bLane;
        #pragma unroll
        for (int t = 0; t < 8; ++t) {
            short8 bf = *(const short8*)(Bc + t * 512);
            acc[t] = __builtin_amdgcn_mfma_f32_16x16x32_bf16(af, bf, acc[t], 0, 0, 0);
        }
    }
    const int row0 = rowBase + quad * 4;
    #pragma unroll
    for (int t = 0; t < 8; ++t) {
        float bc = bp1[t * 16 + cl];
        #pragma unroll
        for (int g = 0; g < 4; ++g) {
            int r = row0 + g;
            if (r < N_NODES)
                Y[r * 128 + t * 16 + cl] = f2bf(fmaxf(acc[t][g] + bc, 0.0f));
        }
    }
}

// ---------------------------------------------------------------------------
// fused: max-pool + dual-GEMM + l2norm + (next-layer y-GEMM | fp32 out).
// R15 change vs R14 (body byte-identical): block = 1 wave / 64 threads,
// grid 3125 (was 2 waves / 1563). Tail arithmetic: 1563 = 256*6+27 ->
// worst-CU 7 blocks vs avg 6.1 (+15%); 3125 = 256*12+53 -> 13 vs 12.2
// (+6.6%). R14's identical mechanism delivered 73.5->68.3; expected here
// ~2-3us/dispatch. Resident waves/CU unchanged (12.2).
// ---------------------------------------------------------------------------
template <bool A0F32, bool LAST>
__device__ __forceinline__ void do_fused(int task, unsigned short* ldsAll,
    const void* __restrict__ A0,
    const unsigned short* __restrict__ Yl,
    const int* __restrict__ deg,
    const unsigned short* __restrict__ csr16,
    const unsigned short* __restrict__ B0, const unsigned short* __restrict__ B1,
    const float* __restrict__ bias,
    unsigned short* __restrict__ outH, float* __restrict__ outF,
    const unsigned short* __restrict__ Bnext, const float* __restrict__ bnext,
    unsigned short* __restrict__ Yout)
{
    constexpr int NT = LAST ? 4 : 8;
    constexpr int N = NT * 16;

    const int lane = threadIdx.x & 63;
    const int wv = threadIdx.x >> 6;
    const int cl = lane & 15;
    const int quad = lane >> 4;
    const int nodeBase = task * FNPB + wv * 16;
    unsigned short* plw = ldsAll + wv * (16 * LROW);

    // ---- pool phase: 16 nodes/wave, 4 lanes/node, 32 dims/lane ----
    {
        const int n16 = lane >> 2;          // node within wave [0,16)
        const int g   = lane & 3;           // 64B dim slice [0,4)
        const int node = nodeBase + n16;
        const int nodeC = min(node, N_NODES - 1);
        const int myDeg = (node < N_NODES) ? min(deg[node], CAP) : 0;
        const unsigned short* csrn = csr16 + (nodeC << 6);
        const unsigned short* yg = Yl + g * 32;

        short8 p[4];
        p[0] = (short8){0,0,0,0,0,0,0,0};
        p[1] = p[0]; p[2] = p[0]; p[3] = p[0];

        if (myDeg > 0) {
            unsigned int idxw[16];
            *(uint4*)(idxw +  0) = *(const uint4*)(csrn +  0);
            *(uint4*)(idxw +  4) = *(const uint4*)(csrn +  8);
            *(uint4*)(idxw +  8) = *(const uint4*)(csrn + 16);
            *(uint4*)(idxw + 12) = *(const uint4*)(csrn + 24);
            const int s0 = (int)(idxw[0] & 0xFFFFu);   // edge 0 always valid

            auto eaddr = [&](int jj) -> const unsigned short* {
                int sj = (jj & 1) ? (int)(idxw[jj >> 1] >> 16)
                                  : (int)(idxw[jj >> 1] & 0xFFFFu);
                sj = (jj < myDeg) ? sj : s0;            // cndmask clamp
                return yg + (sj << 7);
            };

            short8 va[8], vb[8];
            issue8(va, eaddr(0),  eaddr(1));
            issue8(vb, eaddr(2),  eaddr(3));
            wait_vm8(va); consume8(p, va); issue8(va, eaddr(4),  eaddr(5));
            wait_vm8(vb); consume8(p, vb); issue8(vb, eaddr(6),  eaddr(7));
            wait_vm8(va); consume8(p, va); issue8(va, eaddr(8),  eaddr(9));
            wait_vm8(vb); consume8(p, vb); issue8(vb, eaddr(10), eaddr(11));
            wait_vm8(va); consume8(p, va); issue8(va, eaddr(12), eaddr(13));
            wait_vm8(vb); consume8(p, vb); issue8(vb, eaddr(14), eaddr(15));
            if (myDeg > 16) {
                wait_vm8(va); consume8(p, va); issue8(va, eaddr(16), eaddr(17));
                wait_vm8(vb); consume8(p, vb); issue8(vb, eaddr(18), eaddr(19));
                wait_vm8(va); consume8(p, va); issue8(va, eaddr(20), eaddr(21));
                wait_vm8(vb); consume8(p, vb); issue8(vb, eaddr(22), eaddr(23));
                wait_vm8(va); consume8(p, va); issue8(va, eaddr(24), eaddr(25));
                wait_vm8(vb); consume8(p, vb); issue8(vb, eaddr(26), eaddr(27));
                wait_vm8(va); consume8(p, va); issue8(va, eaddr(28), eaddr(29));
                wait_vm8(vb); consume8(p, vb); issue8(vb, eaddr(30), eaddr(31));
            }
            wait_vm8(va); consume8(p, va);
            wait_vm0(vb); consume8(p, vb);

            for (int k = 32; k < myDeg; ++k) {         // rare tail (P~1e-4)
                const short8* r = (const short8*)(yg + ((int)csrn[k] << 7));
                p[0] = __builtin_elementwise_max(p[0], r[0]);
                p[1] = __builtin_elementwise_max(p[1], r[1]);
                p[2] = __builtin_elementwise_max(p[2], r[2]);
                p[3] = __builtin_elementwise_max(p[3], r[3]);
            }
        }
        unsigned short* pw = plw + n16 * LROW + g * 32;
        *(short8*)(pw)      = p[0];
        *(short8*)(pw + 8)  = p[1];
        *(short8*)(pw + 16) = p[2];
        *(short8*)(pw + 24) = p[3];
        // no barrier: this wave wrote rows it alone will read (DS in-order)
    }

    const int ar = min(nodeBase + cl, N_NODES - 1);
    const int aBase = ar * 128 + quad * 8;
    const int fBase = cl * LROW + quad * 8;     // LDS A-fragment base
    const int bLane = cl * 32 + quad * 8;

    f32x4 acc[NT];
    #pragma unroll
    for (int t = 0; t < NT; ++t) acc[t] = (f32x4){0.f, 0.f, 0.f, 0.f};

    #pragma unroll
    for (int c = 0; c < 4; ++c) {
        short8 a0 = loadA<A0F32>(A0, aBase + c * 32);
        short8 a1 = *(const short8*)(plw + fBase + c * 32);
        const unsigned short* B0c = B0 + c * (N * 32) + bLane;
        const unsigned short* B1c = B1 + c * (N * 32) + bLane;
        #pragma unroll
        for (int t = 0; t < NT; ++t) {
            short8 bf = *(const short8*)(B0c + t * 512);
            acc[t] = __builtin_amdgcn_mfma_f32_16x16x32_bf16(a0, bf, acc[t], 0, 0, 0);
        }
        #pragma unroll
        for (int t = 0; t < NT; ++t) {
            short8 bf = *(const short8*)(B1c + t * 512);
            acc[t] = __builtin_amdgcn_mfma_f32_16x16x32_bf16(a1, bf, acc[t], 0, 0, 0);
        }
    }

    #pragma unroll
    for (int t = 0; t < NT; ++t) {
        float bc = bias[t * 16 + cl];
        #pragma unroll
        for (int g = 0; g < 4; ++g) acc[t][g] += bc;
    }

    // ---- fused row-wise L2 norm (wave-local shuffles, width-64) ----
    float inv[4];
    #pragma unroll
    for (int g = 0; g < 4; ++g) {
        float s = 0.f;
        #pragma unroll
        for (int t = 0; t < NT; ++t) s += acc[t][g] * acc[t][g];
        s += __shfl_xor(s, 1, 64);
        s += __shfl_xor(s, 2, 64);
        s += __shfl_xor(s, 4, 64);
        s += __shfl_xor(s, 8, 64);
        inv[g] = 1.0f / fmaxf(sqrtf(s), 1e-12f);
    }

    const int row0 = nodeBase + quad * 4;

    if (LAST) {
        #pragma unroll
        for (int t = 0; t < NT; ++t)
            #pragma unroll
            for (int g = 0; g < 4; ++g) {
                int r = row0 + g;
                if (r < N_NODES)
                    outF[r * N + t * 16 + cl] = fmaxf(acc[t][g] * inv[g], 0.0f);
            }
        return;
    }

    // h -> global (next layer's A0) + LDS stage (C-layout -> A-layout)
    #pragma unroll
    for (int t = 0; t < NT; ++t)
        #pragma unroll
        for (int g = 0; g < 4; ++g) {
            int r = row0 + g;
            unsigned short h = f2bf(fmaxf(acc[t][g] * inv[g], 0.0f));
            if (r < N_NODES) outH[r * 128 + t * 16 + cl] = h;
            plw[(quad * 4 + g) * LROW + t * 16 + cl] = h;
        }

    // ---- y-GEMM for the next layer ----
    f32x4 ya[8];
    #pragma unroll
    for (int t = 0; t < 8; ++t) ya[t] = (f32x4){0.f, 0.f, 0.f, 0.f};
    #pragma unroll
    for (int c = 0; c < 4; ++c) {
        short8 af = *(const short8*)(plw + cl * LROW + c * 32 + quad * 8);
        const unsigned short* Bc = Bnext + c * 4096 + bLane;
        #pragma unroll
        for (int t = 0; t < 8; ++t) {
            short8 bf = *(const short8*)(Bc + t * 512);
            ya[t] = __builtin_amdgcn_mfma_f32_16x16x32_bf16(af, bf, ya[t], 0, 0, 0);
        }
    }
    #pragma unroll
    for (int t = 0; t < 8; ++t) {
        float bc = bnext[t * 16 + cl];
        #pragma unroll
        for (int g = 0; g < 4; ++g) {
            int r = row0 + g;
            if (r < N_NODES)
                Yout[r * 128 + t * 16 + cl] = f2bf(fmaxf(ya[t][g] + bc, 0.0f));
        }
    }
}

template <bool A0F32, bool LAST>
__global__ __launch_bounds__(FTPB) void fused_kernel(
    const void* __restrict__ A0,
    const unsigned short* __restrict__ Yl,
    const int* __restrict__ deg,
    const unsigned short* __restrict__ csr16,
    const unsigned short* __restrict__ B0, const unsigned short* __restrict__ B1,
    const float* __restrict__ bias,
    unsigned short* __restrict__ outH, float* __restrict__ outF,
    const unsigned short* __restrict__ Bnext, const float* __restrict__ bnext,
    unsigned short* __restrict__ Yout)
{
    __shared__ unsigned short lds[FWAVES][16 * LROW];   // 4.4 KB
    do_fused<A0F32, LAST>(blockIdx.x, &lds[0][0], A0, Yl, deg, csr16,
                          B0, B1, bias, outH, outF, Bnext, bnext, Yout);
}

extern "C" void kernel_launch(void* const* d_in, const int* in_sizes, int n_in,
                              void* d_out, int out_size, void* d_ws, size_t ws_size,
                              hipStream_t stream) {
    const float* x    = (const float*)d_in[0];
    const int*   esrc = (const int*)d_in[1];
    const int*   edst = (const int*)d_in[2];
    const float* Wp[3], *bp[3], *Ws[3], *Wn[3], *bb[3];
    for (int l = 0; l < 3; ++l) {
        Wp[l] = (const float*)d_in[3 + 5 * l];
        bp[l] = (const float*)d_in[4 + 5 * l];
        Ws[l] = (const float*)d_in[5 + 5 * l];
        Wn[l] = (const float*)d_in[6 + 5 * l];
        bb[l] = (const float*)d_in[7 + 5 * l];
    }

    const int NF = N_NODES * 128;
    unsigned short* YA  = (unsigned short*)d_ws;     // y ping
    unsigned short* YB  = YA + NF;                   // y pong
    unsigned short* PL  = YB + NF;                   // (unused; kept for layout)
    unsigned short* H1  = PL + NF;                   // h1
    unsigned short* H2  = H1 + NF;                   // h2
    unsigned short* Wpk = H2 + NF;                   // 9 * 16384 packed weights
    int* deg = (int*)(Wpk + 9 * 16384);              // 50000
    unsigned short* csr16 = (unsigned short*)(deg + N_NODES); // 50000*64

    auto WH = [&](int i) { return Wpk + i * 16384; };
    // order: 0=Wp1 1=Ws1 2=Wn1 3=Wp2 4=Ws2 5=Wn2 6=Wp3 7=Ws3 8=Wn3

    WDescs wd;
    wd.W[0] = Wp[0]; wd.N[0] = 128;
    wd.W[1] = Ws[0]; wd.N[1] = 128;
    wd.W[2] = Wn[0]; wd.N[2] = 128;
    wd.W[3] = Wp[1]; wd.N[3] = 128;
    wd.W[4] = Ws[1]; wd.N[4] = 128;
    wd.W[5] = Wn[1]; wd.N[5] = 128;
    wd.W[6] = Wp[2]; wd.N[6] = 128;
    wd.W[7] = Ws[2]; wd.N[7] = 64;
    wd.W[8] = Wn[2]; wd.N[8] = 64;

    // 1) prep: pack weights + zero deg
    prep_kernel<<<576, 256, 0, stream>>>(wd, Wpk, deg);
    // 2) Y1 = relu(x@Wp1+bp1) + one-shot CSR fill (R1 best-measured form)
    mix_kernel<<<GEMMB + CSRB, 256, 0, stream>>>(esrc, edst, deg, csr16,
                                                 x, WH(0), bp[0], YA);
    // 3) layer 1 (pool fused): gathers YA, A0 = x (fp32)
    fused_kernel<true, false><<<FGRID, FTPB, 0, stream>>>(
        x, YA, deg, csr16, WH(1), WH(2), bb[0], H1, nullptr, WH(3), bp[1], YB);
    // 4) layer 2: gathers YB, A0 = H1
    fused_kernel<false, false><<<FGRID, FTPB, 0, stream>>>(
        H1, YB, deg, csr16, WH(4), WH(5), bb[1], H2, nullptr, WH(6), bp[2], YA);
    // 5) layer 3: gathers YA, A0 = H2, fp32 out
    fused_kernel<false, true><<<FGRID, FTPB, 0, stream>>>(
        H2, YA, deg, csr16, WH(7), WH(8), bb[2], nullptr, (float*)d_out,
        nullptr, nullptr, nullptr);
}